// Round 1
// 117.974 us; speedup vs baseline: 1.4351x; 1.4351x over previous
//
#include <hip/hip_runtime.h>

#define NN  512
#define DD  128
#define NTASK_B 8448          // per-batch wave-tasks: 16 * (1+2+...+32)
#define NWAVES  2048          // 512 blocks * 4 waves

typedef __attribute__((ext_vector_type(4))) float f32x4;
typedef __attribute__((ext_vector_type(8))) short s16x8;   // 8 bf16 (4 VGPRs)

#define MFMA(a, b, c) __builtin_amdgcn_mfma_f32_16x16x32_bf16((a), (b), (c), 0, 0, 0)

// LDS strides (ushort units for B, float units for h1): padded -> worst 2-way (free)
#define B1S 136   // 128 + 8
#define B2S 72    // 64 + 8
#define H1S 68    // 64 + 4

// fp32 -> (bf16 hi [RNA], bf16 lo [trunc of exact remainder]); hh+lh+hl ~2^-17 rel
__device__ inline void split8(const float* __restrict__ x, s16x8& h, s16x8& l) {
    uint4 hp, lp;
    unsigned* hw = (unsigned*)&hp;
    unsigned* lw = (unsigned*)&lp;
    #pragma unroll
    for (int i = 0; i < 4; ++i) {
        float x0 = x[2 * i], x1 = x[2 * i + 1];
        unsigned t0 = __float_as_uint(x0) + 0x8000u;
        unsigned t1 = __float_as_uint(x1) + 0x8000u;
        hw[i] = __builtin_amdgcn_perm(t1, t0, 0x07060302u);
        float l0 = x0 - __uint_as_float(t0 & 0xFFFF0000u);
        float l1 = x1 - __uint_as_float(t1 & 0xFFFF0000u);
        lw[i] = __builtin_amdgcn_perm(__float_as_uint(l1), __float_as_uint(l0), 0x07060302u);
    }
    h = __builtin_bit_cast(s16x8, hp);
    l = __builtin_bit_cast(s16x8, lp);
}

__device__ inline void split1(float x, unsigned short& hs, unsigned short& ls) {
    unsigned t = __float_as_uint(x) + 0x8000u;
    hs = (unsigned short)(t >> 16);
    float lo = x - __uint_as_float(t & 0xFFFF0000u);
    ls = (unsigned short)(__float_as_uint(lo) >> 16);
}

// ---------------------------------------------------------------------------
// Kernel A: symmetric logits. 512 persistent blocks, 4 waves each.
// Wave-task = (b, i, 16-wide j-tile with j0 <= (i & ~15)). Lower triangle at
// 16-col granularity; each logit written to [i][j] (coalesced) and [j][i]
// (mirror scatter). Diagonal-tile overlaps write identical bits (benign).
// ---------------------------------------------------------------------------
__global__ __launch_bounds__(256, 2)
void adj_sym(const float* __restrict__ v,
             const float* __restrict__ W1,
             const float* __restrict__ b1,
             const float* __restrict__ W2,
             const float* __restrict__ b2,
             const float* __restrict__ W3,
             const float* __restrict__ b3,
             float* __restrict__ out)
{
    // 61440 B -> 2 blocks/CU; h1_s rows are WAVE-PRIVATE (no barriers in loop)
    __shared__ __attribute__((aligned(16))) unsigned short B1h_s[64 * B1S];
    __shared__ __attribute__((aligned(16))) unsigned short B1l_s[64 * B1S];
    __shared__ __attribute__((aligned(16))) unsigned short B2h_s[32 * B2S];
    __shared__ __attribute__((aligned(16))) unsigned short B2l_s[32 * B2S];
    __shared__ __attribute__((aligned(16))) float h1_s[64 * H1S];

    const int t    = threadIdx.x;
    const int w    = t >> 6;
    const int lane = t & 63;
    const int m16  = t & 15;
    const int q    = (t & 63) >> 4;
    const int q8   = q * 8;

    // ---- prologue: split W1/W2 into LDS (once per block, ~16.5 tasks) ----
    #pragma unroll
    for (int e = 0; e < 32; ++e) {       // W1: 64x128
        int idx = e * 256 + t;
        unsigned short hs, ls;
        split1(W1[idx], hs, ls);
        int o = idx >> 7, d = idx & 127;
        B1h_s[o * B1S + d] = hs;
        B1l_s[o * B1S + d] = ls;
    }
    #pragma unroll
    for (int e = 0; e < 8; ++e) {        // W2: 32x64
        int idx = e * 256 + t;
        unsigned short hs, ls;
        split1(W2[idx], hs, ls);
        int c2 = idx >> 6, k = idx & 63;
        B2h_s[c2 * B2S + k] = hs;
        B2l_s[c2 * B2S + k] = ls;
    }

    float b1v[4];
    #pragma unroll
    for (int ot = 0; ot < 4; ++ot) b1v[ot] = b1[ot * 16 + m16];
    const float b2v0 = b2[m16];
    const float b2v1 = b2[16 + m16];
    const float w3v0 = W3[m16];
    const float w3v1 = W3[16 + m16];
    const float b3v  = b3[0];

    __syncthreads();   // B1/B2 ready; waves drift freely afterwards

    // ---- static per-wave chunk of the 33792 wave-tasks ----
    const int g    = blockIdx.x * 4 + w;       // global wave 0..2047
    int       tk   = (33 * g) >> 1;            // 16.5 tasks/wave
    const int tend = (33 * (g + 1)) >> 1;

    // initial decode: tk -> (bb, G, s, gj); task r = 8G(G+1) + s(G+1) + gj
    // i = 16G + s (row), j0 = 16*gj (col tile), gj <= G
    unsigned bb = (unsigned)tk / (unsigned)NTASK_B;
    int r = tk - (int)(bb * NTASK_B);
    int G = (int)((__fsqrt_rn((float)(2 * r + 1)) - 1.0f) * 0.25f);
    if (G < 0) G = 0;
    while (8 * (G + 1) * (G + 2) <= r) ++G;
    while (G > 0 && 8 * G * (G + 1) > r) --G;
    int rem = r - 8 * G * (G + 1);
    int s   = rem / (G + 1);
    int gj  = rem - s * (G + 1);
    bool newi = true;

    float yv[4][8];

    #pragma unroll 1
    for (; tk < tend; ++tk) {
        const int    i  = (G << 4) + s;
        const int    j0 = gj << 4;
        const size_t vb = ((size_t)bb << 9);

        if (newi) {   // v_i slice (reused across the same-i run of j-tiles)
            const float* __restrict__ vip = v + (vb + i) * DD;
            #pragma unroll
            for (int kt = 0; kt < 4; ++kt) {
                *(float4*)&yv[kt][0] = *(const float4*)(vip + kt * 32 + q8);
                *(float4*)&yv[kt][4] = *(const float4*)(vip + kt * 32 + q8 + 4);
            }
        }

        // A-row slice: row j0+m16, k = kt*32+q8..+7
        const float* __restrict__ vr = v + (vb + j0 + m16) * DD;
        float xr[4][8];
        #pragma unroll
        for (int kt = 0; kt < 4; ++kt) {
            *(float4*)&xr[kt][0] = *(const float4*)(vr + kt * 32 + q8);
            *(float4*)&xr[kt][4] = *(const float4*)(vr + kt * 32 + q8 + 4);
        }

        // ======== layer 1: 16 pairs x 64 cols, K=128 ========
        f32x4 c[4];
        #pragma unroll
        for (int ot = 0; ot < 4; ++ot) c[ot] = (f32x4){0.f, 0.f, 0.f, 0.f};

        #pragma unroll
        for (int kt = 0; kt < 4; ++kt) {
            float d8[8];
            #pragma unroll
            for (int ii = 0; ii < 8; ++ii) d8[ii] = fabsf(yv[kt][ii] - xr[kt][ii]);
            s16x8 ah, al;
            split8(d8, ah, al);
            #pragma unroll
            for (int ot = 0; ot < 4; ++ot) {
                const int n = ot * 16 + m16;
                s16x8 bh = *(const s16x8*)(B1h_s + n * B1S + kt * 32 + q8);
                s16x8 bl = *(const s16x8*)(B1l_s + n * B1S + kt * 32 + q8);
                c[ot] = MFMA(ah, bh, c[ot]);
                c[ot] = MFMA(al, bh, c[ot]);
                c[ot] = MFMA(ah, bl, c[ot]);
            }
        }

        // bias + leaky -> wave-private h1 rows
        #pragma unroll
        for (int ot = 0; ot < 4; ++ot)
            #pragma unroll
            for (int rr = 0; rr < 4; ++rr) {
                float hv = c[ot][rr] + b1v[ot];
                hv = fmaxf(hv, 0.1f * hv);
                h1_s[(w * 16 + q * 4 + rr) * H1S + ot * 16 + m16] = hv;
            }

        // ======== layer 2: 16 pairs x 32 cols, K=64 ========
        f32x4 dacc[2];
        dacc[0] = (f32x4){0.f, 0.f, 0.f, 0.f};
        dacc[1] = (f32x4){0.f, 0.f, 0.f, 0.f};
        #pragma unroll
        for (int kt2 = 0; kt2 < 2; ++kt2) {
            const float* hp = h1_s + (w * 16 + m16) * H1S + kt2 * 32 + q8;
            float a8[8];
            *(float4*)&a8[0] = *(const float4*)(hp);
            *(float4*)&a8[4] = *(const float4*)(hp + 4);
            s16x8 ah, al;
            split8(a8, ah, al);
            #pragma unroll
            for (int ot2 = 0; ot2 < 2; ++ot2) {
                const int n = ot2 * 16 + m16;
                s16x8 bh = *(const s16x8*)(B2h_s + n * B2S + kt2 * 32 + q8);
                s16x8 bl = *(const s16x8*)(B2l_s + n * B2S + kt2 * 32 + q8);
                dacc[ot2] = MFMA(ah, bh, dacc[ot2]);
                dacc[ot2] = MFMA(al, bh, dacc[ot2]);
                dacc[ot2] = MFMA(ah, bl, dacc[ot2]);
            }
        }

        // ======== layer 3 + 16-lane reduce -> 16 logits ========
        float sval[4];
        #pragma unroll
        for (int r2 = 0; r2 < 4; ++r2) {
            float h0  = dacc[0][r2] + b2v0;  h0  = fmaxf(h0, 0.1f * h0);
            float h1v = dacc[1][r2] + b2v1;  h1v = fmaxf(h1v, 0.1f * h1v);
            float sc = fmaf(w3v0, h0, w3v1 * h1v);
            sc += __shfl_xor(sc, 1, 64);
            sc += __shfl_xor(sc, 2, 64);
            sc += __shfl_xor(sc, 4, 64);
            sc += __shfl_xor(sc, 8, 64);
            sval[r2] = sc + b3v;             // pair q*4+r2, all 16 lanes of group
        }
        // re-lane: lane L should hold pair p = L&15.
        // lane L currently holds pairs (L>>4)*4 + {0..3}; select r=L&3 then
        // bpermute from src S with q(S)=p>>2, S&3=p&3.
        const int p = lane & 15;
        float vv = sval[0];
        vv = ((lane & 3) == 1) ? sval[1] : vv;
        vv = ((lane & 3) == 2) ? sval[2] : vv;
        vv = ((lane & 3) == 3) ? sval[3] : vv;
        const float pv = __shfl(vv, ((p >> 2) << 4) | (p & 3), 64);

        if (lane < 32) {
            const size_t addr = (lane < 16)
                ? (vb + (unsigned)i) * NN + (unsigned)(j0 + p)        // direct row (64B)
                : (vb + (unsigned)(j0 + p)) * NN + (unsigned)i;       // mirror scatter
            out[addr] = pv;
        }

        // ---- incremental task advance (no div/sqrt in steady state) ----
        ++gj;
        newi = false;
        if (gj > G) {
            gj = 0; newi = true;
            if (++s == 16) {
                s = 0;
                if (++G == 32) { G = 0; ++bb; }
            }
        }
    }
}

// ---------------------------------------------------------------------------
// Kernel B: in-place row softmax over the 512 logits of each (b,i) row.
// Same math as the previous fused epilogue -> identical numerics.
// ---------------------------------------------------------------------------
__global__ __launch_bounds__(256)
void row_softmax(float* __restrict__ out)
{
    __shared__ float red[8];
    const int t    = threadIdx.x;
    const int w    = t >> 6;
    const int lane = t & 63;

    float* orow = out + (size_t)blockIdx.x * NN;
    float a0 = orow[t];
    float a1 = orow[t + 256];

    float m = fmaxf(a0, a1);
    #pragma unroll
    for (int sh = 32; sh > 0; sh >>= 1)
        m = fmaxf(m, __shfl_xor(m, sh, 64));
    if (lane == 0) red[w] = m;
    __syncthreads();
    const float M = fmaxf(fmaxf(red[0], red[1]), fmaxf(red[2], red[3]));

    float e0 = __expf(a0 - M);
    float e1 = __expf(a1 - M);
    float s01 = e0 + e1;
    #pragma unroll
    for (int sh = 32; sh > 0; sh >>= 1)
        s01 += __shfl_xor(s01, sh, 64);
    if (lane == 0) red[4 + w] = s01;
    __syncthreads();
    const float S = (red[4] + red[5]) + (red[6] + red[7]);
    const float inv = 1.0f / S;

    orow[t]       = e0 * inv;
    orow[t + 256] = e1 * inv;
}

extern "C" void kernel_launch(void* const* d_in, const int* in_sizes, int n_in,
                              void* d_out, int out_size, void* d_ws, size_t ws_size,
                              hipStream_t stream) {
    const float* v  = (const float*)d_in[0];
    const float* W1 = (const float*)d_in[1];
    const float* b1 = (const float*)d_in[2];
    const float* W2 = (const float*)d_in[3];
    const float* b2 = (const float*)d_in[4];
    const float* W3 = (const float*)d_in[5];
    const float* b3 = (const float*)d_in[6];
    float* out = (float*)d_out;

    adj_sym<<<dim3(512), dim3(256), 0, stream>>>(v, W1, b1, W2, b2, W3, b3, out);
    row_softmax<<<dim3(4 * NN), dim3(256), 0, stream>>>(out);
}